// Round 6
// baseline (91.479 us; speedup 1.0000x reference)
//
#include <hip/hip_runtime.h>
#include <hip/hip_bf16.h>

// ModConv2d: per-sample modulated 3x3 conv (N=8, C=64->64, 256x256) + MLPs.
// Kernel 1: MLPs -> w_bf[n][kidx][cb][cout][8ci] (bf16, A-frag 16B units) + bias.
// Kernel 2: implicit-GEMM conv, builtin mfma_f32_32x32x16_bf16.
//   Block: 1024 thr (16 waves), 2 output rows x 256 cols x 64 couts. Grid 1024.
//   Wave (wr, jt): row h0+wr, cols jt*32..+31; acc[2] 32x32 tiles = 32 AGPR
//   -> 4 waves/SIMD from one block (launch_bounds(1024,4), unified 128 regs).
//   ALL weights in LDS (73.7 KB once); x LDS [4 rows][2 half][258][16B] dbuf 66 KB.
//   Staging: each thread 1 row, 16 f32 loads; ISSUE at kidx7 of chunk c-1,
//   WRITE at kidx6 of chunk c (full-chunk latency cover), 1 barrier/chunk.

typedef short bf16x8 __attribute__((ext_vector_type(8)));
typedef float f32x16 __attribute__((ext_vector_type(16)));

#define NB 8
#define CIN 64
#define COUT 64
#define HH 256
#define WW 256
#define HWP (HH * WW)
#define AUXD 128
#define HIDD 256

#define XH 4128             // half-ci plane: 258 * 16B
#define XRW (2 * XH)        // staged row: 8256 B
#define XBUF (4 * XRW)      // 33024 B
#define WOFF (2 * XBUF)     // 66048
#define WBYTES (9 * 8 * 64 * 16)  // 73728
#define SMEMB (WOFF + WBYTES)     // 139776

__device__ __forceinline__ unsigned short f2bf(float f) {
    unsigned u = __builtin_bit_cast(unsigned, f);
    u += 0x7FFFu + ((u >> 16) & 1u);   // RNE
    return (unsigned short)(u >> 16);
}

__device__ __forceinline__ unsigned pk2(float a, float b, float vm) {
    return (unsigned)f2bf(a * vm) | ((unsigned)f2bf(b * vm) << 16);
}

// ---------------- Kernel 1: MLPs ----------------
__global__ __launch_bounds__(256) void mlp_kernel(
    const float* __restrict__ y, const float* __restrict__ weight,
    const float* __restrict__ fc_w1, const float* __restrict__ fc_b1,
    const float* __restrict__ fc_prelu,
    const float* __restrict__ fc_w2, const float* __restrict__ fc_b2,
    const float* __restrict__ bias_w1, const float* __restrict__ bias_b1,
    const float* __restrict__ bias_prelu,
    const float* __restrict__ bias_w2, const float* __restrict__ bias_b2,
    unsigned short* __restrict__ w_bf, float* __restrict__ bvec)
{
    const int n = blockIdx.y;
    const int c = blockIdx.x;
    const int tid = threadIdx.x;
    __shared__ float ylds[AUXD];
    __shared__ float hl[HIDD];
    if (tid < AUXD) ylds[tid] = y[n * AUXD + tid];
    __syncthreads();

    if (c < 16) {
        float s = fc_b1[tid];
        const float* wrow = fc_w1 + tid * AUXD;
        #pragma unroll 4
        for (int a = 0; a < AUXD; ++a) s += ylds[a] * wrow[a];
        float ap = fc_prelu[0];
        hl[tid] = s >= 0.f ? s : ap * s;
        __syncthreads();

        int o = c * 256 + tid;           // o = cout*64 + ci
        float t = fc_b2[o];
        const float* w2row = fc_w2 + o * HIDD;
        #pragma unroll 4
        for (int h = 0; h < HIDD; ++h) t += hl[h] * w2row[h];
        float mod = 1.f / (1.f + expf(-t));
        int cout = o >> 6, ci = o & 63;
        int cb = ci >> 3, cl = ci & 7;
        #pragma unroll
        for (int k = 0; k < 9; ++k) {
            float wv = weight[o * 9 + k];
            // 16B unit = ((n*9+k)*8 + cb)*64 + cout; halfword cl
            w_bf[((((n * 9 + k) * 8 + cb) * 64 + cout) << 3) + cl] = f2bf(mod * wv);
        }
    } else {
        float s = bias_b1[tid];
        const float* wrow = bias_w1 + tid * AUXD;
        #pragma unroll 4
        for (int a = 0; a < AUXD; ++a) s += ylds[a] * wrow[a];
        float ap = bias_prelu[0];
        hl[tid] = s >= 0.f ? s : ap * s;
        __syncthreads();
        if (tid < COUT) {
            float t = bias_b2[tid];
            const float* w2row = bias_w2 + tid * HIDD;
            #pragma unroll 4
            for (int h = 0; h < HIDD; ++h) t += hl[h] * w2row[h];
            bvec[n * COUT + tid] = t;
        }
    }
}

// ---------------- Kernel 2: conv ----------------
#define ISSUE(ci0) { _Pragma("unroll") \
    for (int i = 0; i < 16; ++i) st[i] = xrow[(size_t)((ci0) + i) * HWP]; }

#define WRITE(buf) { \
    unsigned char* dst = (buf) + rg * XRW + (sw + 1) * 16; \
    uint4 lo, hi; \
    lo.x = pk2(st[0], st[1], vm);  lo.y = pk2(st[2], st[3], vm); \
    lo.z = pk2(st[4], st[5], vm);  lo.w = pk2(st[6], st[7], vm); \
    hi.x = pk2(st[8], st[9], vm);  hi.y = pk2(st[10], st[11], vm); \
    hi.z = pk2(st[12], st[13], vm); hi.w = pk2(st[14], st[15], vm); \
    *(uint4*)dst = lo; *(uint4*)(dst + XH) = hi; }

__global__ __launch_bounds__(1024, 4) void conv_kernel(
    const float* __restrict__ x, const unsigned short* __restrict__ w_bf,
    const float* __restrict__ bvec, float* __restrict__ out)
{
    __shared__ __align__(16) unsigned char smem[SMEMB];

    const int bid = blockIdx.x;
    const int n = bid & 7;              // sample -> XCD (x/weights L2 locality)
    const int h0 = (bid >> 3) * 2;      // first output row

    const int tid = threadIdx.x;
    const int lane = tid & 63;
    const int wave = tid >> 6;
    const int wr = wave >> 3;           // output row 0..1
    const int jt = wave & 7;            // 32-col tile
    const int l5 = lane >> 5;           // K half
    const int l31 = lane & 31;

    const int sw = tid & 255;           // staging col
    const int rg = tid >> 8;            // staged input row index 0..3

    // this thread's staging row (clamped + zero mask at image edges)
    const int hin = h0 - 1 + rg;
    const bool val = (hin >= 0) && (hin < HH);
    const float vm = val ? 1.f : 0.f;
    const float* xrow = x + (size_t)n * CIN * HWP + (size_t)(val ? hin : 0) * WW + sw;

    // ---- stage ALL weights for this sample into LDS (A-frag linear layout) ----
    {
        const uint4* wsrc = (const uint4*)w_bf + (size_t)n * (9 * 8 * 64);
        #pragma unroll
        for (int it = 0; it < 5; ++it) {
            int idx = it * 1024 + tid;
            if (idx < 9 * 8 * 64) {
                uint4 v = wsrc[idx];
                *(uint4*)(smem + WOFF + (idx << 4)) = v;
            }
        }
    }

    // zero halo entries (w-index 0 and 257): 4 rows x 2 halves x 2 sides x 2 bufs
    if (tid < 32) {
        int buf = tid >> 4, side = (tid >> 3) & 1, r = (tid >> 1) & 3, hf = tid & 1;
        uint4 z; z.x = z.y = z.z = z.w = 0u;
        *(uint4*)(smem + buf * XBUF + r * XRW + hf * XH + (side ? 257 : 0) * 16) = z;
    }

    // prologue: stage chunk 0 (ci 0..15) into buf0, then issue chunk 1 loads
    float st[16];
    ISSUE(0);
    WRITE(smem);
    ISSUE(16);

    // acc init = per-cout bias (D row = (reg&3) + 8*(reg>>2) + 4*l5)
    f32x16 acc[2];
    #pragma unroll
    for (int m = 0; m < 2; ++m)
        #pragma unroll
        for (int reg = 0; reg < 16; ++reg)
            acc[m][reg] = bvec[n * COUT + m * 32 + (reg & 3) + 8 * (reg >> 2) + 4 * l5];

    __syncthreads();

    for (int c = 0; c < 4; ++c) {
        const int p = c & 1;
        const unsigned char* rbuf = smem + p * XBUF;
        unsigned char* nx = smem + (p ^ 1) * XBUF;

        #pragma unroll
        for (int kidx = 0; kidx < 9; ++kidx) {
            const int kh = kidx / 3, kw = kidx % 3;
            // A-frags from LDS: lane holds A[cout = m*32+l31][k = 8*l5 + j]
            const unsigned char* ab = smem + WOFF +
                (((kidx * 8 + c * 2 + l5) * 64 + l31) << 4);
            bf16x8 aA = *(const bf16x8*)ab;
            bf16x8 aB = *(const bf16x8*)(ab + 512);
            // B-frag: lane holds B[k = 8*l5+j][col = l31] = x[wr+kh][col+kw]
            bf16x8 b0 = *(const bf16x8*)(rbuf + (wr + kh) * XRW + l5 * XH +
                                         (jt * 32 + l31 + kw) * 16);

            if (c < 3 && kidx == 6) { WRITE(nx); }         // chunk c+1 -> other buf
            if (c < 2 && kidx == 7) { ISSUE((c + 2) * 16); } // loads for chunk c+2

            acc[0] = __builtin_amdgcn_mfma_f32_32x32x16_bf16(aA, b0, acc[0], 0, 0, 0);
            acc[1] = __builtin_amdgcn_mfma_f32_32x32x16_bf16(aB, b0, acc[1], 0, 0, 0);
        }
        __syncthreads();
    }

    // epilogue: D col = l31, row = (reg&3) + 8*(reg>>2) + 4*l5
    const int hout = h0 + wr;
    float* ob = out + ((size_t)n * COUT * HH + hout) * WW;
    const int colb = jt * 32 + l31;
    #pragma unroll
    for (int m = 0; m < 2; ++m) {
        #pragma unroll
        for (int reg = 0; reg < 16; ++reg) {
            int cout = m * 32 + (reg & 3) + 8 * (reg >> 2) + 4 * l5;
            ob[(size_t)cout * HWP + colb] = acc[m][reg];
        }
    }
}

extern "C" void kernel_launch(void* const* d_in, const int* in_sizes, int n_in,
                              void* d_out, int out_size, void* d_ws, size_t ws_size,
                              hipStream_t stream) {
    const float* x          = (const float*)d_in[0];
    const float* y          = (const float*)d_in[1];
    const float* weight     = (const float*)d_in[2];
    const float* fc_w1      = (const float*)d_in[3];
    const float* fc_b1      = (const float*)d_in[4];
    const float* fc_prelu   = (const float*)d_in[5];
    const float* fc_w2      = (const float*)d_in[6];
    const float* fc_b2      = (const float*)d_in[7];
    const float* bias_w1    = (const float*)d_in[8];
    const float* bias_b1    = (const float*)d_in[9];
    const float* bias_prelu = (const float*)d_in[10];
    const float* bias_w2    = (const float*)d_in[11];
    const float* bias_b2    = (const float*)d_in[12];
    float* out = (float*)d_out;

    unsigned short* w_bf = (unsigned short*)d_ws;                       // 589824 B
    float* bvec = (float*)((char*)d_ws + (size_t)NB * 9 * 64 * 64 * 2); // 2048 B

    hipLaunchKernelGGL(mlp_kernel, dim3(17, 8), dim3(256), 0, stream,
                       y, weight, fc_w1, fc_b1, fc_prelu, fc_w2, fc_b2,
                       bias_w1, bias_b1, bias_prelu, bias_w2, bias_b2, w_bf, bvec);
    hipLaunchKernelGGL(conv_kernel, dim3(1024), dim3(1024), 0, stream,
                       x, w_bf, bvec, out);
}